// Round 1
// 12489.598 us; speedup vs baseline: 1.0640x; 1.0640x over previous
//
#include <hip/hip_runtime.h>
#include <hip/hip_bf16.h>

#define N_NODES 40962
#define N_EDGES 327680
#define NDIM 256
#define EDIM 64
#define HDIM 512
#define NLAYERS 16

using bf16_t = __bf16;
using bf16x4 = __bf16 __attribute__((ext_vector_type(4)));
using bf16x8 = __bf16 __attribute__((ext_vector_type(8)));
using f32x4  = float __attribute__((ext_vector_type(4)));

__device__ __forceinline__ int clamp_idx(int v) {
    return v < 0 ? 0 : (v >= N_NODES ? N_NODES - 1 : v);
}

__device__ __forceinline__ bf16x8 zero8() {
    bf16x8 z;
#pragma unroll
    for (int j = 0; j < 8; ++j) z[j] = (bf16_t)0.f;
    return z;
}

// ---------------------------------------------------------------------------
// Weight repack: W[l][k][n] (fp32 KxN) -> bf16 MFMA B-fragment order.
// ---------------------------------------------------------------------------
__global__ void repack_w(const float* __restrict__ src, bf16_t* __restrict__ dst,
                         int K, int N, int tilesPer) {
    int idx = blockIdx.x * 256 + threadIdx.x;
    int lane = idx & 63;
    int t = idx >> 6;
    int l = t / tilesPer;
    int tile = t % tilesPer;
    if (l >= NLAYERS) return;
    int ntN = N >> 4;
    int k0 = (tile / ntN) << 5;
    int n0 = (tile % ntN) << 4;
    int k = k0 + (lane >> 4) * 8;
    int n = n0 + (lane & 15);
    const float* s = src + (size_t)l * K * N + (size_t)k * N + n;
    bf16x8 v;
#pragma unroll
    for (int j = 0; j < 8; ++j) v[j] = (bf16_t)s[(size_t)j * N];
    *(bf16x8*)(dst + (size_t)idx * 8) = v;
}

__global__ void init_e2(const float* __restrict__ ef, bf16_t* __restrict__ es, int n8) {
    const size_t per = (size_t)N_EDGES * EDIM;
    for (int i = blockIdx.x * 256 + threadIdx.x; i < n8; i += gridDim.x * 256) {
        float4 a = *(const float4*)(ef + (size_t)i * 8);
        float4 b = *(const float4*)(ef + (size_t)i * 8 + 4);
        bf16x8 v;
        v[0] = (bf16_t)a.x; v[1] = (bf16_t)a.y; v[2] = (bf16_t)a.z; v[3] = (bf16_t)a.w;
        v[4] = (bf16_t)b.x; v[5] = (bf16_t)b.y; v[6] = (bf16_t)b.z; v[7] = (bf16_t)b.w;
        *(bf16x8*)(es + (size_t)i * 8) = v;
        *(bf16x8*)(es + per + (size_t)i * 8) = v;
    }
}

__global__ void f32_to_bf16(const float* __restrict__ src, bf16_t* __restrict__ dst, int n8) {
    for (int i = blockIdx.x * 256 + threadIdx.x; i < n8; i += gridDim.x * 256) {
        float4 a = *(const float4*)(src + (size_t)i * 8);
        float4 b = *(const float4*)(src + (size_t)i * 8 + 4);
        bf16x8 v;
        v[0] = (bf16_t)a.x; v[1] = (bf16_t)a.y; v[2] = (bf16_t)a.z; v[3] = (bf16_t)a.w;
        v[4] = (bf16_t)b.x; v[5] = (bf16_t)b.y; v[6] = (bf16_t)b.z; v[7] = (bf16_t)b.w;
        *(bf16x8*)(dst + (size_t)i * 8) = v;
    }
}

__global__ void zero_f32(float* __restrict__ p, int n4) {
    float4 z; z.x = z.y = z.z = z.w = 0.f;
    for (int i = blockIdx.x * 256 + threadIdx.x; i < n4; i += gridDim.x * 256)
        *(float4*)(p + (size_t)i * 4) = z;
}

// ---------------------------------------------------------------------------
// One-time CSR build over dst (edge_index constant across layers & batches).
// ---------------------------------------------------------------------------
__global__ void hist_k(const int* __restrict__ eidx, int* __restrict__ deg) {
    int e = blockIdx.x * 256 + threadIdx.x;
    if (e < N_EDGES) atomicAdd(&deg[clamp_idx(eidx[N_EDGES + e])], 1);
}

__global__ void scan_k(const int* __restrict__ deg, int* __restrict__ off,
                       int* __restrict__ cur) {
    __shared__ int part[1024];
    const int t = threadIdx.x;
    const int C = (N_NODES + 1023) / 1024;   // 41
    int lo = t * C, hi = min((t + 1) * C, N_NODES);
    int s = 0;
    for (int i = lo; i < hi; ++i) s += deg[i];
    part[t] = s;
    __syncthreads();
    for (int d = 1; d < 1024; d <<= 1) {
        int v = (t >= d) ? part[t - d] : 0;
        __syncthreads();
        part[t] += v;
        __syncthreads();
    }
    int base = (t == 0) ? 0 : part[t - 1];
    for (int i = lo; i < hi; ++i) {
        off[i] = base;
        cur[i] = base;
        base += deg[i];
    }
    if (t == 1023) off[N_NODES] = part[1023];
}

__global__ void fill_k(const int* __restrict__ eidx, int* __restrict__ cur,
                       int* __restrict__ csr) {
    int e = blockIdx.x * 256 + threadIdx.x;
    if (e < N_EDGES) {
        int d = clamp_idx(eidx[N_EDGES + e]);
        int pos = atomicAdd(&cur[d], 1);
        csr[pos] = e;
    }
}

// ---------------------------------------------------------------------------
// Edge kernel, 512 threads (8 waves), 64-edge tile. No atomics.
//   Gathers bf16 x mirror; writes e residual via LDS-staged coalesced stores.
// ---------------------------------------------------------------------------
__global__ __launch_bounds__(512, 4)
void edge_kernel(const bf16_t* __restrict__ x16, bf16_t* __restrict__ es,
                 const int* __restrict__ eidx,
                 const bf16_t* __restrict__ w1p, const float* __restrict__ b1,
                 const bf16_t* __restrict__ w2p, const float* __restrict__ b2,
                 const float* __restrict__ gw, const float* __restrict__ bw) {
    __shared__ bf16_t smem[64 * 584];   // A: stride 584; H: stride 520; tail: red
    __shared__ int sSrc[64], sDst[64];
    float* red = (float*)(smem + 64 * 520);   // 64 rows x 4 floats

    const int b   = blockIdx.y;
    const int e0  = blockIdx.x * 64;
    const int tid = threadIdx.x;

    const bf16_t* xb = x16 + (size_t)b * N_NODES * NDIM;
    bf16_t* eb = es + (size_t)b * N_EDGES * EDIM;

    if (tid < 64) {
        sSrc[tid] = clamp_idx(eidx[e0 + tid]);
        sDst[tid] = clamp_idx(eidx[N_EDGES + e0 + tid]);
    }
    __syncthreads();

    // gather A = [e | x_src | x_dst], all bf16x8 direct (no cvt)
    {   // e rows: 512 chunks, one per thread
        int r = tid >> 3, c = (tid & 7) << 3;
        *(bf16x8*)&smem[r * 584 + c] = *(const bf16x8*)(eb + (size_t)(e0 + r) * EDIM + c);
    }
#pragma unroll
    for (int k = 0; k < 4; ++k) {      // x_src: 64 rows x 32 bf16x8
        int i = tid + k * 512;
        int r = i >> 5, c = (i & 31) << 3;
        *(bf16x8*)&smem[r * 584 + 64 + c] = *(const bf16x8*)(xb + (size_t)sSrc[r] * NDIM + c);
    }
#pragma unroll
    for (int k = 0; k < 4; ++k) {      // x_dst
        int i = tid + k * 512;
        int r = i >> 5, c = (i & 31) << 3;
        *(bf16x8*)&smem[r * 584 + 320 + c] = *(const bf16x8*)(xb + (size_t)sDst[r] * NDIM + c);
    }
    __syncthreads();

    const int wv = tid >> 6, lane = tid & 63;
    const int m16 = lane & 15, quad = lane >> 4;

    // ---- MLP1: M=64, K=576, N=512. wave wv -> cols [wv*64, +64)
    float bias1[4];
#pragma unroll
    for (int nt = 0; nt < 4; ++nt) bias1[nt] = b1[wv * 64 + nt * 16 + m16];

    f32x4 acc1[4][4];
#pragma unroll
    for (int mt = 0; mt < 4; ++mt)
#pragma unroll
        for (int nt = 0; nt < 4; ++nt) acc1[mt][nt] = (f32x4){0.f, 0.f, 0.f, 0.f};

    const bf16x8* W1 = (const bf16x8*)w1p;
#pragma unroll 2
    for (int kc = 0; kc < 18; ++kc) {
        bf16x8 af[4];
#pragma unroll
        for (int mt = 0; mt < 4; ++mt)
            af[mt] = *(const bf16x8*)&smem[(mt * 16 + m16) * 584 + kc * 32 + quad * 8];
        bf16x8 bfr[4];
#pragma unroll
        for (int nt = 0; nt < 4; ++nt)
            bfr[nt] = W1[(size_t)(kc * 32 + wv * 4 + nt) * 64 + lane];
#pragma unroll
        for (int mt = 0; mt < 4; ++mt)
#pragma unroll
            for (int nt = 0; nt < 4; ++nt)
                acc1[mt][nt] = __builtin_amdgcn_mfma_f32_16x16x32_bf16(af[mt], bfr[nt], acc1[mt][nt], 0, 0, 0);
    }
    __syncthreads();   // all waves done reading A before H aliases it

#pragma unroll
    for (int mt = 0; mt < 4; ++mt)
#pragma unroll
        for (int nt = 0; nt < 4; ++nt)
#pragma unroll
            for (int r = 0; r < 4; ++r) {
                int row = mt * 16 + quad * 4 + r;
                int col = wv * 64 + nt * 16 + m16;
                float v = acc1[mt][nt][r] + bias1[nt];
                v = v / (1.f + __expf(-v));
                smem[row * 520 + col] = (bf16_t)v;
            }
    __syncthreads();

    // ---- MLP2: M=64, K=512, N=64. wave (strip, nh): rows [strip*16,+16), cols [nh*32,+32)
    const int strip = wv >> 1, nh = wv & 1;
    f32x4 acc2[2];
#pragma unroll
    for (int nt = 0; nt < 2; ++nt) acc2[nt] = (f32x4){0.f, 0.f, 0.f, 0.f};
    const bf16x8* W2 = (const bf16x8*)w2p;
#pragma unroll 2
    for (int kc = 0; kc < 16; ++kc) {
        bf16x8 a2 = *(const bf16x8*)&smem[(strip * 16 + m16) * 520 + kc * 32 + quad * 8];
#pragma unroll
        for (int nt = 0; nt < 2; ++nt) {
            bf16x8 b2f = W2[(size_t)(kc * 4 + nh * 2 + nt) * 64 + lane];
            acc2[nt] = __builtin_amdgcn_mfma_f32_16x16x32_bf16(a2, b2f, acc2[nt], 0, 0, 0);
        }
    }

    // epilogue: bias + LN(64) partials (this wave covers 32 of 64 cols)
    float bias2[2], g2[2], bl2[2];
#pragma unroll
    for (int nt = 0; nt < 2; ++nt) {
        int c = nh * 32 + nt * 16 + m16;
        bias2[nt] = b2[c];
        g2[nt]    = gw[c];
        bl2[nt]   = bw[c];
    }
    float v[4][2];
#pragma unroll
    for (int r = 0; r < 4; ++r) {
        float s1 = 0.f, s2 = 0.f;
#pragma unroll
        for (int nt = 0; nt < 2; ++nt) {
            v[r][nt] = acc2[nt][r] + bias2[nt];
            s1 += v[r][nt]; s2 += v[r][nt] * v[r][nt];
        }
#pragma unroll
        for (int off = 1; off < 16; off <<= 1) {
            s1 += __shfl_xor(s1, off);
            s2 += __shfl_xor(s2, off);
        }
        if (m16 == 0) {
            int row = strip * 16 + quad * 4 + r;
            red[row * 4 + nh * 2 + 0] = s1;
            red[row * 4 + nh * 2 + 1] = s2;
        }
    }
    __syncthreads();   // red ready; H region now dead -> reuse [0,4096) for e_out

#pragma unroll
    for (int r = 0; r < 4; ++r) {
        int row = strip * 16 + quad * 4 + r;
        float s1 = red[row * 4 + 0] + red[row * 4 + 2];
        float s2 = red[row * 4 + 1] + red[row * 4 + 3];
        float mean = s1 * (1.f / 64.f);
        float var  = s2 * (1.f / 64.f) - mean * mean;
        float rstd = rsqrtf(fmaxf(var, 0.f) + 1e-5f);
        int eid = e0 + row;
        const bf16_t* ebr = eb + (size_t)eid * EDIM;
#pragma unroll
        for (int nt = 0; nt < 2; ++nt) {
            int c = nh * 32 + nt * 16 + m16;
            float ln = (v[r][nt] - mean) * rstd * g2[nt] + bl2[nt];
            float en = (float)ebr[c] + ln;
            smem[row * 64 + c] = (bf16_t)en;
        }
    }
    __syncthreads();
    {   // coalesced e write: 512 x 16B
        int r = tid >> 3, c = (tid & 7) << 3;
        *(bf16x8*)(eb + (size_t)(e0 + r) * EDIM + c) = *(bf16x8*)&smem[r * 64 + c];
    }
}

// ---------------------------------------------------------------------------
// Node kernel, 512 threads (8 waves), 64-node tile.
//   Computes agg inline via CSR gather over e (no atomics, no agg buffer).
//   Writes fp32 residual state AND bf16 x mirror.
// ---------------------------------------------------------------------------
__global__ __launch_bounds__(512, 4)
void node_kernel(float* __restrict__ xs, bf16_t* __restrict__ x16,
                 const bf16_t* __restrict__ es,
                 const int* __restrict__ off, const int* __restrict__ csr,
                 const bf16_t* __restrict__ w1p, const float* __restrict__ b1,
                 const bf16_t* __restrict__ w2p, const float* __restrict__ b2,
                 const float* __restrict__ gw, const float* __restrict__ bw) {
    __shared__ bf16_t smem[64 * 528];   // A: stride 328; H: stride 520; tail: red
    float* red = (float*)(smem + 64 * 520);

    const int b   = blockIdx.y;
    const int n0  = blockIdx.x * 64;
    const int tid = threadIdx.x;

    float* xb = xs + (size_t)b * N_NODES * NDIM;
    bf16_t* xhb = x16 + (size_t)b * N_NODES * NDIM;
    const bf16_t* eb = es + (size_t)b * N_EDGES * EDIM;

    const int wv = tid >> 6, lane = tid & 63;
    const int m16 = lane & 15, quad = lane >> 4;

#pragma unroll
    for (int k = 0; k < 4; ++k) {      // x: 64 rows x 32 bf16x8 from mirror
        int i = tid + k * 512;
        int r = i >> 5, c = (i & 31) << 3;
        int node = n0 + r;
        bf16x8 v = (node < N_NODES) ? *(const bf16x8*)(xhb + (size_t)node * NDIM + c)
                                    : zero8();
        *(bf16x8*)&smem[r * 328 + c] = v;
    }
    // agg via CSR: wave wv handles rows [wv*8, +8); lane = column
#pragma unroll 1
    for (int rr = 0; rr < 8; ++rr) {
        int row = wv * 8 + rr;
        int node = n0 + row;
        float acc = 0.f;
        if (node < N_NODES) {
            int js = off[node], je = off[node + 1];
            for (int j = js; j < je; ++j) {
                int eid = csr[j];
                acc += (float)eb[(size_t)eid * EDIM + lane];
            }
        }
        smem[row * 328 + 256 + lane] = (bf16_t)acc;
    }
    __syncthreads();

    // ---- MLP1: M=64, K=320, N=512
    float bias1[4];
#pragma unroll
    for (int nt = 0; nt < 4; ++nt) bias1[nt] = b1[wv * 64 + nt * 16 + m16];

    f32x4 acc1[4][4];
#pragma unroll
    for (int mt = 0; mt < 4; ++mt)
#pragma unroll
        for (int nt = 0; nt < 4; ++nt) acc1[mt][nt] = (f32x4){0.f, 0.f, 0.f, 0.f};

    const bf16x8* W1 = (const bf16x8*)w1p;
#pragma unroll 2
    for (int kc = 0; kc < 10; ++kc) {
        bf16x8 af[4];
#pragma unroll
        for (int mt = 0; mt < 4; ++mt)
            af[mt] = *(const bf16x8*)&smem[(mt * 16 + m16) * 328 + kc * 32 + quad * 8];
        bf16x8 bfr[4];
#pragma unroll
        for (int nt = 0; nt < 4; ++nt)
            bfr[nt] = W1[(size_t)(kc * 32 + wv * 4 + nt) * 64 + lane];
#pragma unroll
        for (int mt = 0; mt < 4; ++mt)
#pragma unroll
            for (int nt = 0; nt < 4; ++nt)
                acc1[mt][nt] = __builtin_amdgcn_mfma_f32_16x16x32_bf16(af[mt], bfr[nt], acc1[mt][nt], 0, 0, 0);
    }
    __syncthreads();

#pragma unroll
    for (int mt = 0; mt < 4; ++mt)
#pragma unroll
        for (int nt = 0; nt < 4; ++nt)
#pragma unroll
            for (int r = 0; r < 4; ++r) {
                int row = mt * 16 + quad * 4 + r;
                int col = wv * 64 + nt * 16 + m16;
                float v = acc1[mt][nt][r] + bias1[nt];
                v = v / (1.f + __expf(-v));
                smem[row * 520 + col] = (bf16_t)v;
            }
    __syncthreads();

    // ---- MLP2: M=64, K=512, N=256. wave (strip, nh): rows [strip*16,+16), cols [nh*128,+128)
    const int strip = wv >> 1, nh = wv & 1;
    f32x4 acc2[8];
#pragma unroll
    for (int nt = 0; nt < 8; ++nt) acc2[nt] = (f32x4){0.f, 0.f, 0.f, 0.f};
    const bf16x8* W2 = (const bf16x8*)w2p;
#pragma unroll 2
    for (int kc = 0; kc < 16; ++kc) {
        bf16x8 a2 = *(const bf16x8*)&smem[(strip * 16 + m16) * 520 + kc * 32 + quad * 8];
#pragma unroll
        for (int nt = 0; nt < 8; ++nt) {
            bf16x8 b2f = W2[(size_t)(kc * 16 + nh * 8 + nt) * 64 + lane];
            acc2[nt] = __builtin_amdgcn_mfma_f32_16x16x32_bf16(a2, b2f, acc2[nt], 0, 0, 0);
        }
    }

    float bias2[8], g8[8], bl8[8];
#pragma unroll
    for (int nt = 0; nt < 8; ++nt) {
        int c = nh * 128 + nt * 16 + m16;
        bias2[nt] = b2[c];
        g8[nt]    = gw[c];
        bl8[nt]   = bw[c];
    }
    float v[4][8];
#pragma unroll
    for (int r = 0; r < 4; ++r) {
        float s1 = 0.f, s2 = 0.f;
#pragma unroll
        for (int nt = 0; nt < 8; ++nt) {
            v[r][nt] = acc2[nt][r] + bias2[nt];
            s1 += v[r][nt]; s2 += v[r][nt] * v[r][nt];
        }
#pragma unroll
        for (int off2 = 1; off2 < 16; off2 <<= 1) {
            s1 += __shfl_xor(s1, off2);
            s2 += __shfl_xor(s2, off2);
        }
        if (m16 == 0) {
            int row = strip * 16 + quad * 4 + r;
            red[row * 4 + nh * 2 + 0] = s1;
            red[row * 4 + nh * 2 + 1] = s2;
        }
    }
    __syncthreads();

#pragma unroll
    for (int r = 0; r < 4; ++r) {
        int row = strip * 16 + quad * 4 + r;
        int node = n0 + row;
        if (node >= N_NODES) continue;
        float s1 = red[row * 4 + 0] + red[row * 4 + 2];
        float s2 = red[row * 4 + 1] + red[row * 4 + 3];
        float mean = s1 * (1.f / 256.f);
        float var  = s2 * (1.f / 256.f) - mean * mean;
        float rstd = rsqrtf(fmaxf(var, 0.f) + 1e-5f);
#pragma unroll
        for (int nt = 0; nt < 8; ++nt) {
            int c = nh * 128 + nt * 16 + m16;
            float ln = (v[r][nt] - mean) * rstd * g8[nt] + bl8[nt];
            float* px = &xb[(size_t)node * NDIM + c];
            float nv = *px + ln;
            *px = nv;
            xhb[(size_t)node * NDIM + c] = (bf16_t)nv;
        }
    }
}

extern "C" void kernel_launch(void* const* d_in, const int* in_sizes, int n_in,
                              void* d_out, int out_size, void* d_ws, size_t ws_size,
                              hipStream_t stream) {
    const float* nf   = (const float*)d_in[0];
    const float* ef   = (const float*)d_in[1];
    const float* We1  = (const float*)d_in[2];
    const float* be1  = (const float*)d_in[3];
    const float* We2  = (const float*)d_in[4];
    const float* be2  = (const float*)d_in[5];
    const float* ge   = (const float*)d_in[6];
    const float* ble  = (const float*)d_in[7];
    const float* Wn1  = (const float*)d_in[8];
    const float* bn1  = (const float*)d_in[9];
    const float* Wn2  = (const float*)d_in[10];
    const float* bn2  = (const float*)d_in[11];
    const float* gn   = (const float*)d_in[12];
    const float* bln  = (const float*)d_in[13];
    const int* eidx   = (const int*)d_in[14];

    float* xs = (float*)d_out;   // fp32 x-state accumulates in-place in d_out

    char* p = (char*)d_ws;
    bf16_t* es  = (bf16_t*)p; p += (size_t)2 * N_EDGES * EDIM * 2;
    bf16_t* x16 = (bf16_t*)p; p += (size_t)2 * N_NODES * NDIM * 2;
    bf16_t* w1ep = (bf16_t*)p; p += (size_t)NLAYERS * 576 * 512 * 2;
    bf16_t* w2ep = (bf16_t*)p; p += (size_t)NLAYERS * 512 * 64 * 2;
    bf16_t* w1np = (bf16_t*)p; p += (size_t)NLAYERS * 320 * 512 * 2;
    bf16_t* w2np = (bf16_t*)p; p += (size_t)NLAYERS * 512 * 256 * 2;
    int* deg = (int*)p; p += (size_t)40964 * 4;
    int* off = (int*)p; p += (size_t)40964 * 4;
    int* cur = (int*)p; p += (size_t)40964 * 4;
    int* csr = (int*)p; p += (size_t)N_EDGES * 4;

    repack_w<<<2304, 256, 0, stream>>>(We1, w1ep, 576, 512, 576);
    repack_w<<<256,  256, 0, stream>>>(We2, w2ep, 512, 64,  64);
    repack_w<<<1280, 256, 0, stream>>>(Wn1, w1np, 320, 512, 320);
    repack_w<<<1024, 256, 0, stream>>>(Wn2, w2np, 512, 256, 256);

    hipMemcpyAsync(xs, nf, (size_t)out_size * 4, hipMemcpyDeviceToDevice, stream);
    f32_to_bf16<<<2048, 256, 0, stream>>>(nf, x16, 2 * N_NODES * NDIM / 8);
    init_e2<<<2048, 256, 0, stream>>>(ef, es, N_EDGES * EDIM / 8);

    // one-time CSR over dst
    zero_f32<<<64, 256, 0, stream>>>((float*)deg, 40964 / 4);
    hist_k<<<N_EDGES / 256, 256, 0, stream>>>(eidx, deg);
    scan_k<<<1, 1024, 0, stream>>>(deg, off, cur);
    fill_k<<<N_EDGES / 256, 256, 0, stream>>>(eidx, cur, csr);

    for (int l = 0; l < NLAYERS; ++l) {
        edge_kernel<<<dim3(N_EDGES / 64, 2), 512, 0, stream>>>(
            x16, es, eidx,
            w1ep + (size_t)l * 576 * 512, be1 + l * 512,
            w2ep + (size_t)l * 512 * 64,  be2 + l * 64,
            ge + l * 64, ble + l * 64);
        node_kernel<<<dim3((N_NODES + 63) / 64, 2), 512, 0, stream>>>(
            xs, x16, es, off, csr,
            w1np + (size_t)l * 320 * 512, bn1 + l * 512,
            w2np + (size_t)l * 512 * 256, bn2 + l * 256,
            gn + l * 256, bln + l * 256);
    }
}